// Round 8
// baseline (944.241 us; speedup 1.0000x reference)
//
#include <hip/hip_runtime.h>
#include <math.h>

#define N_NODES 100000
#define N_EDGES 3200000
#define F_NODE 4
#define F_EDGE 4
#define LD 6
#define HID 16
#define NLAYER 8
#define EPSF 1e-6f

#define NPB 64                      // nodes per bucket
#define NBK 1563                    // ceil(N_NODES/64)
#define NBIN 196                    // ceil(N_NODES/512): coarse bins of 512 nodes
#define G1 2000                     // blocks for hist/scatter
#define CH (N_EDGES / G1)           // 1600 edges per block
#define TILE 2048                   // edge_layer LDS tile (records)

// ---------- bf16 helpers (RNE pack, low half = first elem) ----------
__device__ __forceinline__ unsigned f2bf(float a, float b) {
    unsigned ua = __float_as_uint(a);
    ua = (ua + 0x7fffu + ((ua >> 16) & 1u)) >> 16;
    unsigned ub = __float_as_uint(b);
    ub = (ub + 0x7fffu + ((ub >> 16) & 1u)) & 0xffff0000u;
    return ua | ub;
}
__device__ __forceinline__ float bflo(unsigned u) { return __uint_as_float(u << 16); }
__device__ __forceinline__ float bfhi(unsigned u) { return __uint_as_float(u & 0xffff0000u); }

// ==================== phase 1: per-block LDS histograms over 196 coarse bins ====================
__global__ __launch_bounds__(256) void hist_kernel(const int* __restrict__ ei,
                                                   int* __restrict__ ghd,
                                                   int* __restrict__ ghs) {
    __shared__ int hd[NBIN];
    __shared__ int hs[NBIN];
    int t = threadIdx.x, blk = blockIdx.x;
    for (int i = t; i < NBIN; i += 256) { hd[i] = 0; hs[i] = 0; }
    __syncthreads();
    int beg = blk * CH, end = beg + CH;
    for (int e = beg + t; e < end; e += 256) {
        atomicAdd(&hs[ei[e] >> 9], 1);
        atomicAdd(&hd[ei[N_EDGES + e] >> 9], 1);
    }
    __syncthreads();
    for (int i = t; i < NBIN; i += 256) {
        ghd[(size_t)i * G1 + blk] = hd[i];
        ghs[(size_t)i * G1 + blk] = hs[i];
    }
}

// ==================== phase 2a: per-bin scan over blocks (coalesced, bin-major) ====================
__global__ __launch_bounds__(256) void scanb_kernel(int* __restrict__ ghd, int* __restrict__ ghs,
                                                    int* __restrict__ totd, int* __restrict__ tots) {
    __shared__ int part[256];
    int b = blockIdx.x, t = threadIdx.x;
#pragma unroll
    for (int a = 0; a < 2; a++) {
        int* g = a ? ghs : ghd;
        int vals[8];
        int sum = 0;
#pragma unroll
        for (int k = 0; k < 8; k++) {
            int idx = t * 8 + k;
            vals[k] = (idx < G1) ? g[(size_t)b * G1 + idx] : 0;
            sum += vals[k];
        }
        part[t] = sum;
        __syncthreads();
        for (int off = 1; off < 256; off <<= 1) {
            int v = (t >= off) ? part[t - off] : 0;
            __syncthreads();
            part[t] += v;
            __syncthreads();
        }
        int excl = part[t] - sum;
#pragma unroll
        for (int k = 0; k < 8; k++) {
            int idx = t * 8 + k;
            if (idx < G1) g[(size_t)b * G1 + idx] = excl;
            excl += vals[k];
        }
        if (t == 0) (a ? tots : totd)[b] = part[255];
        __syncthreads();
    }
}

// ==================== phase 2b: exclusive scan of bin totals ====================
__global__ __launch_bounds__(256) void totscan_kernel(const int* __restrict__ totd,
                                                      const int* __restrict__ tots,
                                                      int* __restrict__ binbased,
                                                      int* __restrict__ binbases) {
    __shared__ int part[256];
    int t = threadIdx.x;
#pragma unroll
    for (int a = 0; a < 2; a++) {
        const int* tot = a ? tots : totd;
        int* base = a ? binbases : binbased;
        int v = (t < NBIN) ? tot[t] : 0;
        part[t] = v;
        __syncthreads();
        for (int off = 1; off < 256; off <<= 1) {
            int u = (t >= off) ? part[t - off] : 0;
            __syncthreads();
            part[t] += u;
            __syncthreads();
        }
        if (t < NBIN) base[t] = part[t] - v;
        if (t == 0) base[NBIN] = N_EDGES;
        __syncthreads();
    }
}

// ==================== phase 3: coarse binned scatter (8B dst records + 4B src words) ====================
// recA = {src | nib<<17, e} ; sbufA = e | snib<<22
__global__ __launch_bounds__(256) void scatterA_kernel(const int* __restrict__ ei,
                                                       const int* __restrict__ ghd,
                                                       const int* __restrict__ ghs,
                                                       const int* __restrict__ binbased,
                                                       const int* __restrict__ binbases,
                                                       uint2* __restrict__ recA,
                                                       unsigned* __restrict__ sbufA) {
    __shared__ int curd[NBIN];
    __shared__ int curs[NBIN];
    int t = threadIdx.x, blk = blockIdx.x;
    for (int i = t; i < NBIN; i += 256) {
        curd[i] = binbased[i] + ghd[(size_t)i * G1 + blk];
        curs[i] = binbases[i] + ghs[(size_t)i * G1 + blk];
    }
    __syncthreads();
    int beg = blk * CH, end = beg + CH;
    for (int e = beg + t; e < end; e += 256) {
        int s = ei[e], d = ei[N_EDGES + e];
        int p = atomicAdd(&curd[d >> 9], 1);
        recA[p] = make_uint2((unsigned)s | ((unsigned)(d & 511) << 17), (unsigned)e);
        int q = atomicAdd(&curs[s >> 9], 1);
        sbufA[q] = (unsigned)e | ((unsigned)(s & 511) << 22);
    }
}

// ==================== phase 4a: per-bin sort by dst node; emit final rec + degInv + bucket bases ====================
__global__ __launch_bounds__(256) void sortrec_kernel(const uint2* __restrict__ recA,
                                                      const float* __restrict__ ea,
                                                      const int* __restrict__ binbased,
                                                      uint4* __restrict__ recB,
                                                      float* __restrict__ degInv,
                                                      int* __restrict__ based_bk) {
    __shared__ int hist[512];
    __shared__ int cur[512];
    __shared__ int part[256];
    int b = blockIdx.x, t = threadIdx.x;
    hist[t] = 0;
    hist[t + 256] = 0;
    __syncthreads();
    int beg = binbased[b], end = binbased[b + 1];
    for (int i = beg + t; i < end; i += 256)
        atomicAdd(&hist[(recA[i].x >> 17) & 511u], 1);
    __syncthreads();
    int s0 = hist[2 * t], s1 = hist[2 * t + 1];
    int tsum = s0 + s1;
    part[t] = tsum;
    __syncthreads();
    for (int off = 1; off < 256; off <<= 1) {
        int v = (t >= off) ? part[t - off] : 0;
        __syncthreads();
        part[t] += v;
        __syncthreads();
    }
    int excl = part[t] - tsum;
    cur[2 * t] = beg + excl;
    cur[2 * t + 1] = beg + excl + s0;
    __syncthreads();
    int node0 = b << 9;
    for (int j = t; j < 512; j += 256) {
        int node = node0 + j;
        if (node < N_NODES) degInv[node] = 1.0f / fmaxf((float)hist[j], 1.0f);
    }
    if (t < 8) {
        int node = node0 + t * 64;
        if (node < N_NODES) based_bk[(b << 3) + t] = cur[t * 64];
    }
    if (b == NBIN - 1 && t == 0) based_bk[NBK] = N_EDGES;
    __syncthreads();
    for (int i = beg + t; i < end; i += 256) {
        uint2 r = recA[i];
        int nib = (int)((r.x >> 17) & 511u);
        unsigned s = r.x & 0x1FFFFu;
        unsigned e = r.y;
        int p = atomicAdd(&cur[nib], 1);
        float4 ev = reinterpret_cast<const float4*>(ea)[e];
        recB[p] = make_uint4(s | ((unsigned)(nib & 63) << 17),
                             f2bf(ev.x, ev.y), f2bf(ev.z, ev.w), e);
    }
}

// ==================== phase 4b: per-bin sort of src words; emit sorted sbuf + src bucket bases ====================
__global__ __launch_bounds__(256) void sortsrc_kernel(const unsigned* __restrict__ sbufA,
                                                      const int* __restrict__ binbases,
                                                      unsigned* __restrict__ sbufB,
                                                      int* __restrict__ bases_bk) {
    __shared__ int hist[512];
    __shared__ int cur[512];
    __shared__ int part[256];
    int b = blockIdx.x, t = threadIdx.x;
    hist[t] = 0;
    hist[t + 256] = 0;
    __syncthreads();
    int beg = binbases[b], end = binbases[b + 1];
    for (int i = beg + t; i < end; i += 256)
        atomicAdd(&hist[(sbufA[i] >> 22) & 511u], 1);
    __syncthreads();
    int s0 = hist[2 * t], s1 = hist[2 * t + 1];
    int tsum = s0 + s1;
    part[t] = tsum;
    __syncthreads();
    for (int off = 1; off < 256; off <<= 1) {
        int v = (t >= off) ? part[t - off] : 0;
        __syncthreads();
        part[t] += v;
        __syncthreads();
    }
    int excl = part[t] - tsum;
    cur[2 * t] = beg + excl;
    cur[2 * t + 1] = beg + excl + s0;
    __syncthreads();
    if (t < 8) {
        int node = (b << 9) + t * 64;
        if (node < N_NODES) bases_bk[(b << 3) + t] = cur[t * 64];
    }
    if (b == NBIN - 1 && t == 0) bases_bk[NBK] = N_EDGES;
    __syncthreads();
    for (int i = beg + t; i < end; i += 256) {
        unsigned w = sbufA[i];
        int nib = (int)((w >> 22) & 511u);
        int p = atomicAdd(&cur[nib], 1);
        sbufB[p] = (w & 0x3FFFFFu) | ((unsigned)(nib & 63) << 22);
    }
}

// ==================== layer-0 A/B tables ====================
__global__ __launch_bounds__(256) void ab_init(const float* __restrict__ x,
                                               const float* __restrict__ W1,
                                               const float* __restrict__ b1,
                                               unsigned* __restrict__ A,
                                               unsigned* __restrict__ B) {
    __shared__ float sW[8 * HID];
    __shared__ float sb[HID];
    int t = threadIdx.x;
    for (int i = t; i < 8 * HID; i += 256) sW[i] = W1[12 * HID + i];
    if (t < HID) sb[t] = b1[t];
    __syncthreads();
    int i = blockIdx.x * 256 + t;
    if (i >= N_NODES) return;
    float4 xv = reinterpret_cast<const float4*>(x)[i];
    float xf[4] = {xv.x, xv.y, xv.z, xv.w};
    float a[HID], bb[HID];
#pragma unroll
    for (int j = 0; j < HID; j++) { a[j] = sb[j]; bb[j] = 0.0f; }
#pragma unroll
    for (int r = 0; r < 4; r++) {
        float v = xf[r];
#pragma unroll
        for (int j = 0; j < HID; j++) {
            a[j]  = fmaf(v, sW[r * HID + j], a[j]);
            bb[j] = fmaf(v, sW[(4 + r) * HID + j], bb[j]);
        }
    }
    uint4* Ao = reinterpret_cast<uint4*>(A + (size_t)i * 8);
    Ao[0] = make_uint4(f2bf(a[0], a[1]), f2bf(a[2], a[3]), f2bf(a[4], a[5]), f2bf(a[6], a[7]));
    Ao[1] = make_uint4(f2bf(a[8], a[9]), f2bf(a[10], a[11]), f2bf(a[12], a[13]), f2bf(a[14], a[15]));
    uint4* Bo = reinterpret_cast<uint4*>(B + (size_t)i * 8);
    Bo[0] = make_uint4(f2bf(bb[0], bb[1]), f2bf(bb[2], bb[3]), f2bf(bb[4], bb[5]), f2bf(bb[6], bb[7]));
    Bo[1] = make_uint4(f2bf(bb[8], bb[9]), f2bf(bb[10], bb[11]), f2bf(bb[12], bb[13]), f2bf(bb[14], bb[15]));
}

// ==================== per-layer: LDS-tiled, run-accumulation (sorted records) ====================
template <int LAST>
__global__ __launch_bounds__(256) void edge_layer(const uint4* __restrict__ recB,
                                                  const unsigned* __restrict__ Ain,
                                                  const unsigned* __restrict__ Bin,
                                                  const float* __restrict__ x,
                                                  const float* __restrict__ degInv,
                                                  const float* __restrict__ W1l,
                                                  const float* __restrict__ W2l,
                                                  const float* __restrict__ b2l,
                                                  const float* __restrict__ W1n,
                                                  const float* __restrict__ b1n,
                                                  const float* __restrict__ Wf,
                                                  const float* __restrict__ bfp,
                                                  const int* __restrict__ based_bk,
                                                  unsigned* __restrict__ Aout,
                                                  unsigned* __restrict__ Bout,
                                                  float* __restrict__ Pout,
                                                  float* __restrict__ Pbuf) {
    __shared__ float sWea[4 * HID];
    __shared__ float sW2[HID * LD];
    __shared__ float sb2[LD];
    __shared__ float sW1n[20 * HID];
    __shared__ float sb1n[HID];
    __shared__ float sWf[LD];
    __shared__ float sbf;
    __shared__ float accf[LD * NPB];
    __shared__ unsigned sB[NPB * 8];
    __shared__ uint4 tile[TILE];
    int t = threadIdx.x;
    int b = blockIdx.x;
    for (int i = t; i < 4 * HID; i += 256) sWea[i] = W1l[20 * HID + i];
    for (int i = t; i < HID * LD; i += 256) sW2[i] = W2l[i];
    if (t < LD) sb2[t] = b2l[t];
    if (!LAST) {
        for (int i = t; i < 20 * HID; i += 256) sW1n[i] = W1n[i];
        if (t < HID) sb1n[t] = b1n[t];
    } else {
        if (t < LD) sWf[t] = Wf[t];
        if (t == 0) sbf = bfp[0];
    }
    for (int i = t; i < LD * NPB; i += 256) accf[i] = 0.0f;
    {
        size_t base8 = (size_t)(b << 6) * 8;
        for (int i = t; i < NPB * 8; i += 256) {
            size_t gi = base8 + i;
            sB[i] = (gi < (size_t)N_NODES * 8) ? Bin[gi] : 0u;
        }
    }
    __syncthreads();

    int beg = based_bk[b], end = based_bk[b + 1];

    for (int base = beg; base < end; base += TILE) {
        int m = end - base;
        if (m > TILE) m = TILE;
        for (int i = t; i < m; i += 256) tile[i] = recB[base + i];
        __syncthreads();
        int K2 = (m + 255) >> 8;
        int q0 = t * K2;
        int q1 = q0 + K2;
        if (q1 > m) q1 = m;
        float acc[LD];
        int cur = -1;
        uint4 bx, by;
#pragma unroll
        for (int o = 0; o < LD; o++) acc[o] = 0.0f;
#pragma unroll 2
        for (int q = q0; q < q1; ++q) {
            uint4 r = tile[q];
            int dl = (int)((r.x >> 17) & 63u);
            if (dl != cur) {
                if (cur >= 0) {
#pragma unroll
                    for (int o = 0; o < LD; o++) atomicAdd(&accf[o * NPB + cur], acc[o]);
                }
                cur = dl;
#pragma unroll
                for (int o = 0; o < LD; o++) acc[o] = 0.0f;
                const uint4* Bp = reinterpret_cast<const uint4*>(sB) + dl * 2;
                bx = Bp[0];
                by = Bp[1];
            }
            int s = (int)(r.x & 0x1FFFFu);
            const uint4* Ap = reinterpret_cast<const uint4*>(Ain + (size_t)s * 8);
            uint4 ax = Ap[0], ay = Ap[1];
            float h[HID];
            h[0]  = bflo(ax.x) + bflo(bx.x);  h[1]  = bfhi(ax.x) + bfhi(bx.x);
            h[2]  = bflo(ax.y) + bflo(bx.y);  h[3]  = bfhi(ax.y) + bfhi(bx.y);
            h[4]  = bflo(ax.z) + bflo(bx.z);  h[5]  = bfhi(ax.z) + bfhi(bx.z);
            h[6]  = bflo(ax.w) + bflo(bx.w);  h[7]  = bfhi(ax.w) + bfhi(bx.w);
            h[8]  = bflo(ay.x) + bflo(by.x);  h[9]  = bfhi(ay.x) + bfhi(by.x);
            h[10] = bflo(ay.y) + bflo(by.y);  h[11] = bfhi(ay.y) + bfhi(by.y);
            h[12] = bflo(ay.z) + bflo(by.z);  h[13] = bfhi(ay.z) + bfhi(by.z);
            h[14] = bflo(ay.w) + bflo(by.w);  h[15] = bfhi(ay.w) + bfhi(by.w);
            float ef[4] = {bflo(r.y), bfhi(r.y), bflo(r.z), bfhi(r.z)};
#pragma unroll
            for (int rr = 0; rr < 4; rr++) {
                float v = ef[rr];
#pragma unroll
                for (int j = 0; j < HID; j++) h[j] = fmaf(v, sWea[rr * HID + j], h[j]);
            }
#pragma unroll
            for (int j = 0; j < HID; j++) h[j] = fmaxf(h[j], 0.0f);
            float mo[LD];
#pragma unroll
            for (int o = 0; o < LD; o++) mo[o] = sb2[o];
#pragma unroll
            for (int j = 0; j < HID; j++) {
                float hj = h[j];
#pragma unroll
                for (int o = 0; o < LD; o++) mo[o] = fmaf(hj, sW2[j * LD + o], mo[o]);
            }
#pragma unroll
            for (int o = 0; o < LD; o++) acc[o] += mo[o];
        }
        if (cur >= 0) {
#pragma unroll
            for (int o = 0; o < LD; o++) atomicAdd(&accf[o * NPB + cur], acc[o]);
        }
        __syncthreads();
    }

    if (t < NPB) {
        int gid = (b << 6) + t;
        if (gid < N_NODES) {
            float inv = degInv[gid];
            float Xv[LD];
#pragma unroll
            for (int o = 0; o < LD; o++) Xv[o] = fmaxf(accf[o * NPB + t] * inv, 0.0f);
            if (LAST) {
                float a2 = sbf;
#pragma unroll
                for (int o = 0; o < LD; o++) a2 = fmaf(Xv[o], sWf[o], a2);
                float P = fmaxf(a2, 0.0f);
                Pout[gid] = P;
                float fx = x[gid * F_NODE + 3];
                Pbuf[gid] = (fx != 0.0f) ? fx : P;
            } else {
                float4 xv = reinterpret_cast<const float4*>(x)[gid];
                float xf[4] = {xv.x, xv.y, xv.z, xv.w};
                float a[HID], bb[HID];
#pragma unroll
                for (int j = 0; j < HID; j++) { a[j] = sb1n[j]; bb[j] = 0.0f; }
#pragma unroll
                for (int rr = 0; rr < LD; rr++) {
                    float v = Xv[rr];
#pragma unroll
                    for (int j = 0; j < HID; j++) {
                        a[j]  = fmaf(v, sW1n[rr * HID + j], a[j]);
                        bb[j] = fmaf(v, sW1n[(LD + rr) * HID + j], bb[j]);
                    }
                }
#pragma unroll
                for (int rr = 0; rr < 4; rr++) {
                    float v = xf[rr];
#pragma unroll
                    for (int j = 0; j < HID; j++) {
                        a[j]  = fmaf(v, sW1n[(12 + rr) * HID + j], a[j]);
                        bb[j] = fmaf(v, sW1n[(16 + rr) * HID + j], bb[j]);
                    }
                }
                uint4* Ao = reinterpret_cast<uint4*>(Aout + (size_t)gid * 8);
                Ao[0] = make_uint4(f2bf(a[0], a[1]), f2bf(a[2], a[3]), f2bf(a[4], a[5]), f2bf(a[6], a[7]));
                Ao[1] = make_uint4(f2bf(a[8], a[9]), f2bf(a[10], a[11]), f2bf(a[12], a[13]), f2bf(a[14], a[15]));
                uint4* Bo = reinterpret_cast<uint4*>(Bout + (size_t)gid * 8);
                Bo[0] = make_uint4(f2bf(bb[0], bb[1]), f2bf(bb[2], bb[3]), f2bf(bb[4], bb[5]), f2bf(bb[6], bb[7]));
                Bo[1] = make_uint4(f2bf(bb[8], bb[9]), f2bf(bb[10], bb[11]), f2bf(bb[12], bb[13]), f2bf(bb[14], bb[15]));
            }
        }
    }
}

// ==================== flows (original order, exact fp32) ====================
__global__ __launch_bounds__(256) void flows_noatomic(const int* __restrict__ ei,
                                                      const float* __restrict__ ea,
                                                      const float* __restrict__ Pbuf,
                                                      float* __restrict__ flows_out) {
    int e = blockIdx.x * 256 + threadIdx.x;
    if (e >= N_EDGES) return;
    int s = ei[e];
    int d = ei[N_EDGES + e];
    float ps = Pbuf[s], pd = Pbuf[d];
    float dp2 = ps * ps - pd * pd;
    float k = ea[(size_t)e * F_EDGE];
    float sg = (dp2 > 0.0f) ? 1.0f : ((dp2 < 0.0f) ? -1.0f : 0.0f);
    flows_out[e] = sg * sqrtf(fabsf(dp2) / k + EPSF);
}

// ==================== balance in-flow: segscan over sorted records ====================
__global__ __launch_bounds__(256) void balance_in(const uint4* __restrict__ recB,
                                                  const float* __restrict__ flows,
                                                  const float* __restrict__ x,
                                                  const int* __restrict__ based_bk,
                                                  float* __restrict__ bal) {
    __shared__ float acc[NPB];
    int t = threadIdx.x;
    if (t < NPB) acc[t] = 0.0f;
    __syncthreads();
    int b = blockIdx.x;
    int beg = based_bk[b], end = based_bk[b + 1];
    int lane = t & 63;
    for (int base = beg; base < end; base += 256) {
        int p = base + t;
        bool valid = p < end;
        int key = -1;
        float f = 0.0f;
        if (valid) {
            uint4 r = recB[p];
            key = (int)((r.x >> 17) & 63u);
            f = flows[r.w];
        }
#pragma unroll
        for (int st = 1; st < 64; st <<= 1) {
            int kup = __shfl_up(key, st, 64);
            float v = __shfl_up(f, st, 64);
            if ((lane >= st) && (kup == key)) f += v;
        }
        int knx = __shfl_down(key, 1, 64);
        bool tail = (lane == 63) || (knx != key);
        if (valid && tail) atomicAdd(&acc[key], f);
    }
    __syncthreads();
    if (t < NPB) {
        int gid = (b << 6) + t;
        if (gid < N_NODES) bal[gid] = acc[t] + x[gid * F_NODE + 0];
    }
}

// ==================== balance out-flow (segscan over sorted sbuf) + imbalance ====================
__global__ __launch_bounds__(256) void balance_out(const unsigned* __restrict__ sbufB,
                                                   const float* __restrict__ flows,
                                                   const int* __restrict__ bases_bk,
                                                   const float* __restrict__ bal,
                                                   float* __restrict__ imb2) {
    __shared__ float acc[NPB];
    int t = threadIdx.x;
    if (t < NPB) acc[t] = 0.0f;
    __syncthreads();
    int b = blockIdx.x;
    int beg = bases_bk[b], end = bases_bk[b + 1];
    int lane = t & 63;
    for (int base = beg; base < end; base += 256) {
        int q = base + t;
        bool valid = q < end;
        int key = -1;
        float f = 0.0f;
        if (valid) {
            unsigned u = sbufB[q];
            key = (int)((u >> 22) & 63u);
            f = flows[u & 0x3FFFFFu];
        }
#pragma unroll
        for (int st = 1; st < 64; st <<= 1) {
            int kup = __shfl_up(key, st, 64);
            float v = __shfl_up(f, st, 64);
            if ((lane >= st) && (kup == key)) f += v;
        }
        int knx = __shfl_down(key, 1, 64);
        bool tail = (lane == 63) || (knx != key);
        if (valid && tail) atomicAdd(&acc[key], f);
    }
    __syncthreads();
    if (t < NPB) {
        float v = 0.0f;
        int gid = (b << 6) + t;
        if (gid < N_NODES) {
            float bv = bal[gid] - acc[t];
            v = bv * bv;
        }
#pragma unroll
        for (int off = 32; off > 0; off >>= 1) v += __shfl_down(v, off, 64);
        if (t == 0) atomicAdd(imb2, v);
    }
}

__global__ void fin_kernel(const float* __restrict__ imb2, float* __restrict__ out) {
    out[0] = sqrtf(imb2[0]);
}

// ==================== launch ====================
extern "C" void kernel_launch(void* const* d_in, const int* in_sizes, int n_in,
                              void* d_out, int out_size, void* d_ws, size_t ws_size,
                              hipStream_t stream) {
    const float* x   = (const float*)d_in[0];
    const float* ea  = (const float*)d_in[1];
    const int*   ei  = (const int*)d_in[2];
    const float* W1  = (const float*)d_in[3];
    const float* b1  = (const float*)d_in[4];
    const float* W2  = (const float*)d_in[5];
    const float* b2  = (const float*)d_in[6];
    const float* Wf  = (const float*)d_in[7];
    const float* bf_ = (const float*)d_in[8];
    float* out = (float*)d_out;

    const size_t N = N_NODES, E = N_EDGES;

    // ---- workspace layout (4B elements), ~107 MB ----
    size_t o = 0;
    auto alloc = [&](size_t n) { size_t r = o; o += (n + 3) & ~(size_t)3; return r; };
    size_t o_recB     = alloc(4 * E);
    size_t o_recA     = alloc(2 * E);     // sbufB overlays this after sortrec
    size_t o_sbufA    = alloc(E);
    size_t o_ghd      = alloc((size_t)NBIN * G1);
    size_t o_ghs      = alloc((size_t)NBIN * G1);
    size_t o_totd     = alloc(NBIN);
    size_t o_tots     = alloc(NBIN);
    size_t o_binbased = alloc(NBIN + 1);
    size_t o_binbases = alloc(NBIN + 1);
    size_t o_basedbk  = alloc(NBK + 1);
    size_t o_basesbk  = alloc(NBK + 1);
    size_t o_degInv   = alloc(N);
    size_t o_A0       = alloc(8 * N);
    size_t o_B0       = alloc(8 * N);
    size_t o_A1       = alloc(8 * N);
    size_t o_B1       = alloc(8 * N);
    size_t o_Pbuf     = alloc(N);
    size_t o_bal      = alloc(N);
    size_t o_imb2     = alloc(16);
    (void)o;

    int* wsi = (int*)d_ws;
    uint4*    recB     = (uint4*)(wsi + o_recB);
    uint2*    recA     = (uint2*)(wsi + o_recA);
    unsigned* sbufA    = (unsigned*)(wsi + o_sbufA);
    unsigned* sbufB    = (unsigned*)(wsi + o_recA);   // overlay
    int*      ghd      = wsi + o_ghd;
    int*      ghs      = wsi + o_ghs;
    int*      totd     = wsi + o_totd;
    int*      tots     = wsi + o_tots;
    int*      binbased = wsi + o_binbased;
    int*      binbases = wsi + o_binbases;
    int*      based_bk = wsi + o_basedbk;
    int*      bases_bk = wsi + o_basesbk;
    float*    degInv   = (float*)(wsi + o_degInv);
    unsigned* A0       = (unsigned*)(wsi + o_A0);
    unsigned* B0       = (unsigned*)(wsi + o_B0);
    unsigned* A1       = (unsigned*)(wsi + o_A1);
    unsigned* B1       = (unsigned*)(wsi + o_B1);
    float*    Pbuf     = (float*)(wsi + o_Pbuf);
    float*    bal      = (float*)(wsi + o_bal);
    float*    imb2     = (float*)(wsi + o_imb2);

    const int NB = (N_NODES + 255) / 256;   // 391
    const int EB = (N_EDGES + 255) / 256;   // 12500

    hipMemsetAsync(imb2, 0, sizeof(float), stream);

    hist_kernel<<<G1, 256, 0, stream>>>(ei, ghd, ghs);
    scanb_kernel<<<NBIN, 256, 0, stream>>>(ghd, ghs, totd, tots);
    totscan_kernel<<<1, 256, 0, stream>>>(totd, tots, binbased, binbases);
    scatterA_kernel<<<G1, 256, 0, stream>>>(ei, ghd, ghs, binbased, binbases, recA, sbufA);
    sortrec_kernel<<<NBIN, 256, 0, stream>>>(recA, ea, binbased, recB, degInv, based_bk);
    sortsrc_kernel<<<NBIN, 256, 0, stream>>>(sbufA, binbases, sbufB, bases_bk);

    ab_init<<<NB, 256, 0, stream>>>(x, W1, b1, A0, B0);

    for (int l = 0; l < NLAYER; l++) {
        const unsigned* Ain = (l & 1) ? A1 : A0;
        const unsigned* Bin = (l & 1) ? B1 : B0;
        unsigned* Aout = (l & 1) ? A0 : A1;
        unsigned* Bout = (l & 1) ? B0 : B1;
        const float* W1l = W1 + (size_t)l * 24 * HID;
        const float* W2l = W2 + (size_t)l * HID * LD;
        const float* b2l = b2 + (size_t)l * LD;
        if (l < NLAYER - 1) {
            edge_layer<0><<<NBK, 256, 0, stream>>>(recB, Ain, Bin, x, degInv, W1l, W2l, b2l,
                                                   W1 + (size_t)(l + 1) * 24 * HID,
                                                   b1 + (size_t)(l + 1) * HID,
                                                   Wf, bf_, based_bk,
                                                   Aout, Bout, out, Pbuf);
        } else {
            edge_layer<1><<<NBK, 256, 0, stream>>>(recB, Ain, Bin, x, degInv, W1l, W2l, b2l,
                                                   W1, b1, Wf, bf_, based_bk,
                                                   Aout, Bout, out, Pbuf);
        }
    }

    flows_noatomic<<<EB, 256, 0, stream>>>(ei, ea, Pbuf, out + N);
    balance_in<<<NBK, 256, 0, stream>>>(recB, out + N, x, based_bk, bal);
    balance_out<<<NBK, 256, 0, stream>>>(sbufB, out + N, bases_bk, bal, imb2);
    fin_kernel<<<1, 1, 0, stream>>>(imb2, out + (size_t)N + E);
}